// Round 11
// baseline (232.371 us; speedup 1.0000x reference)
//
#include <hip/hip_runtime.h>

#define GRID_H 20
#define GRID_W 80
#define NCH 264
#define K 256
#define NPIX 128   // 16x8 glyph pixels
#define HPB 5      // h-rows per block

typedef __attribute__((ext_vector_type(8))) short short8;
typedef __attribute__((ext_vector_type(4))) float f32x4;
typedef __attribute__((ext_vector_type(8))) unsigned short u16x8;

static __device__ __forceinline__ unsigned short f2bf(float f) {
    unsigned int u = __builtin_bit_cast(unsigned int, f);
    u += 0x7FFFu + ((u >> 16) & 1u);   // round-to-nearest-even
    return (unsigned short)(u >> 16);
}

// NOTE: plain 1-arg launch_bounds only. The 2-arg form (min waves/EU)
// miscompiled MFMA accumulation in R2/R3/R7.
__global__ __launch_bounds__(320) void ansi_kernel(
        const float* __restrict__ data,
        const float* __restrict__ cm,
        float* __restrict__ out) {
    // Full B tile (R6-proven layout): 128 px rows x 256 ch, bf16, 512B rows,
    // XOR-swizzle (p&7)<<4. Staged ONCE per block, read-only afterwards.
    __shared__ alignas(16) unsigned short Bl[NPIX * K];           // 64 KB
    // Wave-PRIVATE epilogue staging (R9-proven): [wave][line][slot][x*3+ch]
    __shared__ alignas(16) float S[5][2][16][24];                 // 15 KB
    // total 79 KB -> 2 blocks/CU; B+S only, fgbg goes through shuffles.

    const int blk = blockIdx.x;          // 0..511
    const int b  = blk >> 2;             // batch
    const int hg = blk & 3;              // h-group (5 rows each)
    const int t = threadIdx.x;
    const int wave = t >> 6;
    const int lane = t & 63;
    const int mrow = lane & 15;          // cell within M-tile
    const int g    = lane >> 4;          // k-group
    const int cell0 = wave * 16;

    // ---- stage char_matrix once (R6 verbatim) ----
    for (int i = t; i < NPIX * (K / 8); i += 320) {
        int p  = i & (NPIX - 1);
        int cg = i >> 7;                 // channel group of 8 (0..31)
        const float* src = cm + (size_t)cg * 8 * NPIX + p;
        u16x8 pk;
        #pragma unroll
        for (int j = 0; j < 8; ++j) pk[j] = f2bf(src[j * NPIX]);
        int ba = (p * 512 + cg * 16) ^ ((p & 7) << 4);
        *reinterpret_cast<u16x8*>(reinterpret_cast<char*>(Bl) + ba) = pk;
    }
    __syncthreads();   // the ONLY barrier in the kernel

    #pragma unroll 1
    for (int hh = 0; hh < HPB; ++hh) {
        const int h = hg * HPB + hh;
        const float* dbase = data + (size_t)(b * GRID_H + h) * GRID_W * NCH;

        // ---- fg/bg: lanes 0..15 compute one cell each, distribute via shfl ----
        float fb[6] = {0.f, 0.f, 0.f, 0.f, 0.f, 0.f};
        if (lane < 16) {
            const float* q = dbase + (size_t)(cell0 + lane) * NCH + 256;
            float4 a = *reinterpret_cast<const float4*>(q);      // fg_bold, fg.rgb
            float4 c = *reinterpret_cast<const float4*>(q + 4);  // bg_bold, bg.rgb
            float fs = 0.5f * a.x + 0.5f;
            float bs = 0.5f * c.x + 0.5f;
            fb[0] = bs * c.y; fb[1] = bs * c.z; fb[2] = bs * c.w;
            fb[3] = fs * a.y - fb[0];
            fb[4] = fs * a.z - fb[1];
            fb[5] = fs * a.w - fb[2];
        }
        float bgv[4][3], dv[4][3];
        #pragma unroll
        for (int r = 0; r < 4; ++r) {
            int src = g * 4 + r;         // source lane = local cell index
            #pragma unroll
            for (int j = 0; j < 3; ++j) {
                bgv[r][j] = __shfl(fb[j], src);
                dv[r][j]  = __shfl(fb[3 + j], src);
            }
        }

        // ---- load + pack A (full K=256): 8 x bf16x8 ----
        const float* arow = dbase + (size_t)(cell0 + mrow) * NCH + g * 8;
        short8 apk[8];
        #pragma unroll
        for (int ks = 0; ks < 8; ++ks) {
            float4 a0 = *reinterpret_cast<const float4*>(arow + ks * 32);
            float4 a1 = *reinterpret_cast<const float4*>(arow + ks * 32 + 4);
            u16x8 ap;
            ap[0] = f2bf(a0.x); ap[1] = f2bf(a0.y); ap[2] = f2bf(a0.z); ap[3] = f2bf(a0.w);
            ap[4] = f2bf(a1.x); ap[5] = f2bf(a1.y); ap[6] = f2bf(a1.z); ap[7] = f2bf(a1.w);
            apk[ks] = __builtin_bit_cast(short8, ap);
        }

        f32x4 acc[8];
        #pragma unroll
        for (int n = 0; n < 8; ++n) acc[n] = (f32x4){0.f, 0.f, 0.f, 0.f};

        // ---- GEMM (R6-proven inner loop) ----
        #pragma unroll
        for (int ks = 0; ks < 8; ++ks) {
            const int kbase = ks * 32 + g * 8;
            #pragma unroll
            for (int n = 0; n < 8; ++n) {
                int p = n * 16 + mrow;
                int ba = (p * 512 + kbase * 2) ^ ((p & 7) << 4);
                short8 bfrag = *reinterpret_cast<short8*>(
                    reinterpret_cast<char*>(Bl) + ba);
                acc[n] = __builtin_amdgcn_mfma_f32_16x16x32_bf16(
                    apk[ks], bfrag, acc[n], 0, 0, 0);
            }
        }

        // ---- epilogue (R9-proven): wave-private LDS transpose, no barriers ----
        const int col = lane & 15;
        float4* out4 = (float4*)out;
        const size_t rowf4 = (size_t)(b * 320 + h * 16) * 480 + wave * 96;
        const int line_sel = col >> 3;
        const int x3 = (col & 7) * 3;

        #pragma unroll
        for (int pass = 0; pass < 8; ++pass) {
            // acc[pass] covers pixels pass*16..pass*16+15 = y-lines {2p, 2p+1}
            #pragma unroll
            for (int r = 0; r < 4; ++r) {
                float raw = acc[pass][r];
                float* o = &S[wave][line_sel][r * 4 + g][x3];
                o[0] = bgv[r][0] + raw * dv[r][0];
                o[1] = bgv[r][1] + raw * dv[r][1];
                o[2] = bgv[r][2] + raw * dv[r][2];
            }
            // readback (b128, permuted cell slot) + coalesced global store.
            // Same-wave LDS write->read is in-order; no sync needed.
            const float4* Sw = (const float4*)&S[wave][0][0][0];   // 192 float4
            #pragma unroll
            for (int q = 0; q < 3; ++q) {
                int j = q * 64 + lane;            // 0..191
                int line = (j >= 96) ? 1 : 0;
                int rem = j - 96 * line;          // 0..95 = cell*6 + s
                int c = rem / 6;
                int s = rem - 6 * c;
                float4 v = Sw[line * 96 + ((c & 3) * 4 + (c >> 2)) * 6 + s];
                out4[rowf4 + (size_t)(pass * 2 + line) * 480 + rem] = v;
            }
        }
    }
}

extern "C" void kernel_launch(void* const* d_in, const int* in_sizes, int n_in,
                              void* d_out, int out_size, void* d_ws, size_t ws_size,
                              hipStream_t stream) {
    (void)in_sizes; (void)n_in; (void)d_ws; (void)ws_size; (void)out_size;
    const float* data = (const float*)d_in[0];
    const float* cm   = (const float*)d_in[1];
    float* out        = (float*)d_out;
    const int nblocks = 128 * (GRID_H / HPB);   // 512: one per (b, h-group)
    ansi_kernel<<<nblocks, 320, 0, stream>>>(data, cm, out);
}

// Round 12
// 134.209 us; speedup vs baseline: 1.7314x; 1.7314x over previous
//
#include <hip/hip_runtime.h>

#define GRID_H 20
#define GRID_W 80
#define NCH 264
#define K 256
#define NPIX 128   // 16x8 glyph pixels

typedef __attribute__((ext_vector_type(8))) short short8;
typedef __attribute__((ext_vector_type(4))) float f32x4;
typedef __attribute__((ext_vector_type(8))) unsigned short u16x8;

static __device__ __forceinline__ unsigned short f2bf(float f) {
    unsigned int u = __builtin_bit_cast(unsigned int, f);
    u += 0x7FFFu + ((u >> 16) & 1u);   // round-to-nearest-even
    return (unsigned short)(u >> 16);
}

// Swizzled byte offset within a 32KB pixel-half (R9-proven layout):
// 64 rows (local pixel) x 512B (256 bf16 channels), XOR (pl&7)<<4.
static __device__ __forceinline__ int bswz(int pl, int clbyte) {
    return (pl * 512 + clbyte) ^ ((pl & 7) << 4);
}

// Pack cm (f32 [256 ch][128 px]) -> ws: two 32KB pixel-halves whose LINEAR
// byte order equals the main kernel's swizzled LDS layout, so staging is a
// byte-copy via global_load_lds.
__global__ void prep_kernel(const float* __restrict__ cm,
                            unsigned short* __restrict__ ws) {
    int i = blockIdx.x * 256 + threadIdx.x;   // 0..4095 chunks of 16B
    int p  = i & 127;                         // pixel 0..127
    int c8 = i >> 7;                          // channel-group of 8 (0..31)
    int hf = p >> 6, pl = p & 63;
    u16x8 pk;
    #pragma unroll
    for (int j = 0; j < 8; ++j) pk[j] = f2bf(cm[(c8 * 8 + j) * NPIX + p]);
    *reinterpret_cast<u16x8*>((char*)ws + hf * 32768 + bswz(pl, c8 * 16)) = pk;
}

// NOTE: plain 1-arg launch_bounds only. The 2-arg form (min waves/EU)
// miscompiled MFMA accumulation in R2/R3/R7.
template <bool USE_WS>
__global__ __launch_bounds__(320) void ansi_kernel(
        const float* __restrict__ data,
        const float* __restrict__ cm,
        const unsigned short* __restrict__ ws,
        float* __restrict__ out) {
    // 32 KB: one PIXEL-half of B (R9-proven). Staged per half.
    __shared__ alignas(16) unsigned char ldsB[32768];
    // Wave-PRIVATE epilogue staging (R9-proven): [wave][line][slot][x*3+ch]
    __shared__ alignas(16) float S[5][2][16][24];   // 15 KB; total 47 KB

    const int blk = blockIdx.x;
    const int b = blk / GRID_H;
    const int h = blk % GRID_H;
    const float* dbase = data + (size_t)(b * GRID_H + h) * GRID_W * NCH;
    const int t = threadIdx.x;
    const int wave = t >> 6;
    const int lane = t & 63;
    const int mrow = lane & 15;     // cell within M-tile
    const int g    = lane >> 4;     // k-group
    const int cell0 = wave * 16;

    // ---- fg/bg: lanes 0..15 one cell each, distribute via shfl (R11-proven) ----
    float fb[6] = {0.f, 0.f, 0.f, 0.f, 0.f, 0.f};
    if (lane < 16) {
        const float* q = dbase + (size_t)(cell0 + lane) * NCH + 256;
        float4 a = *reinterpret_cast<const float4*>(q);      // fg_bold, fg.rgb
        float4 c = *reinterpret_cast<const float4*>(q + 4);  // bg_bold, bg.rgb
        float fs = 0.5f * a.x + 0.5f;
        float bs = 0.5f * c.x + 0.5f;
        fb[0] = bs * c.y; fb[1] = bs * c.z; fb[2] = bs * c.w;
        fb[3] = fs * a.y - fb[0];
        fb[4] = fs * a.z - fb[1];
        fb[5] = fs * a.w - fb[2];
    }
    float bgv[4][3], dv[4][3];
    #pragma unroll
    for (int r = 0; r < 4; ++r) {
        int srcl = g * 4 + r;        // source lane = local cell index
        #pragma unroll
        for (int j = 0; j < 3; ++j) {
            bgv[r][j] = __shfl(fb[j], srcl);
            dv[r][j]  = __shfl(fb[3 + j], srcl);
        }
    }

    // ---- load + pack A once (full K=256): 8 x bf16x8 ----
    const float* arow = dbase + (size_t)(cell0 + mrow) * NCH + g * 8;
    short8 apk[8];
    #pragma unroll
    for (int ks = 0; ks < 8; ++ks) {
        float4 a0 = *reinterpret_cast<const float4*>(arow + ks * 32);
        float4 a1 = *reinterpret_cast<const float4*>(arow + ks * 32 + 4);
        u16x8 ap;
        ap[0] = f2bf(a0.x); ap[1] = f2bf(a0.y); ap[2] = f2bf(a0.z); ap[3] = f2bf(a0.w);
        ap[4] = f2bf(a1.x); ap[5] = f2bf(a1.y); ap[6] = f2bf(a1.z); ap[7] = f2bf(a1.w);
        apk[ks] = __builtin_bit_cast(short8, ap);
    }

    f32x4 acc[8];
    #pragma unroll
    for (int n = 0; n < 8; ++n) acc[n] = (f32x4){0.f, 0.f, 0.f, 0.f};

    // ---- GEMM over two pixel-halves; 3 barriers total (R9 structure) ----
    #pragma unroll
    for (int half = 0; half < 2; ++half) {
        if (USE_WS) {
            // async byte-copy: ws linear order == swizzled LDS order
            const char* src = (const char*)ws + half * 32768;
            #pragma unroll
            for (int it = 0; it < 6; ++it) {
                int j = it * 320 + t;
                __builtin_amdgcn_global_load_lds(
                    (const __attribute__((address_space(1))) void*)(src + (size_t)j * 16),
                    (__attribute__((address_space(3))) void*)&ldsB[(it * 320 + wave * 64) * 16],
                    16, 0, 0);
            }
            if (t < 128) {   // tail chunks 1920..2047 (waves 0,1 full)
                int j = 1920 + t;
                __builtin_amdgcn_global_load_lds(
                    (const __attribute__((address_space(1))) void*)(src + (size_t)j * 16),
                    (__attribute__((address_space(3))) void*)&ldsB[(1920 + wave * 64) * 16],
                    16, 0, 0);
            }
        } else {
            // fallback: R9-proven direct gather
            for (int i = t; i < 64 * 32; i += 320) {
                int pl = i & 63;
                int cg = i >> 6;
                const float* src = cm + (size_t)cg * 8 * NPIX + half * 64 + pl;
                u16x8 pk;
                #pragma unroll
                for (int j = 0; j < 8; ++j) pk[j] = f2bf(src[j * NPIX]);
                *reinterpret_cast<u16x8*>(&ldsB[bswz(pl, cg * 16)]) = pk;
            }
        }
        __syncthreads();   // staging visible (drains vmcnt)

        #pragma unroll
        for (int ks = 0; ks < 8; ++ks) {
            const int kbase = ks * 32 + g * 8;
            #pragma unroll
            for (int n = 0; n < 4; ++n) {
                int pl = n * 16 + mrow;       // local pixel row 0..63
                short8 bfrag = *reinterpret_cast<short8*>(&ldsB[bswz(pl, kbase * 2)]);
                acc[half * 4 + n] = __builtin_amdgcn_mfma_f32_16x16x32_bf16(
                    apk[ks], bfrag, acc[half * 4 + n], 0, 0, 0);
            }
        }
        if (half == 0) __syncthreads();   // all waves done reading before restage
    }

    // ---- epilogue (R9-proven): wave-private LDS transpose, zero barriers ----
    const int col = lane & 15;
    float4* out4 = (float4*)out;
    const size_t rowf4 = (size_t)(b * 320 + h * 16) * 480 + wave * 96;
    const int line_sel = col >> 3;
    const int x3 = (col & 7) * 3;

    #pragma unroll
    for (int pass = 0; pass < 8; ++pass) {
        #pragma unroll
        for (int r = 0; r < 4; ++r) {
            float raw = acc[pass][r];
            float* o = &S[wave][line_sel][r * 4 + g][x3];
            o[0] = bgv[r][0] + raw * dv[r][0];
            o[1] = bgv[r][1] + raw * dv[r][1];
            o[2] = bgv[r][2] + raw * dv[r][2];
        }
        const float4* Sw = (const float4*)&S[wave][0][0][0];   // 192 float4
        #pragma unroll
        for (int q = 0; q < 3; ++q) {
            int j = q * 64 + lane;            // 0..191
            int line = (j >= 96) ? 1 : 0;
            int rem = j - 96 * line;          // 0..95 = cell*6 + s
            int c = rem / 6;
            int s = rem - 6 * c;
            float4 v = Sw[line * 96 + ((c & 3) * 4 + (c >> 2)) * 6 + s];
            out4[rowf4 + (size_t)(pass * 2 + line) * 480 + rem] = v;
        }
    }
}

extern "C" void kernel_launch(void* const* d_in, const int* in_sizes, int n_in,
                              void* d_out, int out_size, void* d_ws, size_t ws_size,
                              hipStream_t stream) {
    (void)in_sizes; (void)n_in; (void)out_size;
    const float* data = (const float*)d_in[0];
    const float* cm   = (const float*)d_in[1];
    float* out        = (float*)d_out;
    const int nblocks = 128 * GRID_H;   // one block per (b, h) — R9 grid
    if (ws_size >= 65536) {
        prep_kernel<<<16, 256, 0, stream>>>(cm, (unsigned short*)d_ws);
        ansi_kernel<true><<<nblocks, 320, 0, stream>>>(
            data, cm, (const unsigned short*)d_ws, out);
    } else {
        ansi_kernel<false><<<nblocks, 320, 0, stream>>>(data, cm, nullptr, out);
    }
}